// Round 4
// baseline (5141.673 us; speedup 1.0000x reference)
//
#include <hip/hip_runtime.h>
#include <stdint.h>

typedef __attribute__((ext_vector_type(8))) short bf16x8;
typedef __attribute__((ext_vector_type(4))) short short4v;
typedef __attribute__((ext_vector_type(4))) float f32x4;

#define MFMA16(a, b, c) __builtin_amdgcn_mfma_f32_16x16x32_bf16((a), (b), (c), 0, 0, 0)

__device__ __forceinline__ float b2f(short s) {
  unsigned u = ((unsigned)(unsigned short)s) << 16;
  return __builtin_bit_cast(float, u);
}
__device__ __forceinline__ short f2b(float f) {
  unsigned u = __builtin_bit_cast(unsigned, f);
  u = (u + 0x7fffu + ((u >> 16) & 1u)) >> 16;
  return (short)u;
}

// -------- convert f32 -> bf16 (8 elems/thread) --------
__global__ __launch_bounds__(256) void convert_kernel(const float* __restrict__ src,
                                                      short* __restrict__ dst, int n) {
  int i = (blockIdx.x * 256 + threadIdx.x) * 8;
  if (i >= n) return;
  f32x4 a = *(const f32x4*)(src + i);
  f32x4 b = *(const f32x4*)(src + i + 4);
  short4v o0, o1;
#pragma unroll
  for (int j = 0; j < 4; ++j) { o0[j] = f2b(a[j]); o1[j] = f2b(b[j]); }
  *(short4v*)(dst + i) = o0;
  *(short4v*)(dst + i + 4) = o1;
}

// -------- RMSNorm: f32 in (x trunk), f32 gamma, bf16 out; one block per row of 1024
__global__ __launch_bounds__(256) void rmsnorm_f32(const float* __restrict__ X,
                                                   const float* __restrict__ G,
                                                   short* __restrict__ O) {
  int row = blockIdx.x;
  int t = threadIdx.x;
  f32x4 v = *(const f32x4*)(X + (size_t)row * 1024 + t * 4);
  float ss = 0.f;
#pragma unroll
  for (int j = 0; j < 4; ++j) ss += v[j] * v[j];
#pragma unroll
  for (int d = 1; d < 64; d <<= 1) ss += __shfl_xor(ss, d, 64);
  __shared__ float red[4];
  if ((t & 63) == 0) red[t >> 6] = ss;
  __syncthreads();
  float tot = red[0] + red[1] + red[2] + red[3];
  float rinv = rsqrtf(tot * (1.0f / 1024.0f) + 1e-5f);
  f32x4 g = *(const f32x4*)(G + t * 4);
  short4v o;
#pragma unroll
  for (int j = 0; j < 4; ++j) o[j] = f2b(v[j] * rinv * g[j]);
  *(short4v*)(O + (size_t)row * 1024 + t * 4) = o;
}

// ---------------- GEMM: C = A[M][K] * Bt[N][K]^T, bf16 A/B, f32 acc
// MODE 0: C = AB (bf16 out)
// MODE 1: C = AB + Resf (f32 res, f32 out) -- Resf may alias C (same-element RAW in-thread)
// MODE 2: C = silu(Res_bf16) * AB (bf16 out, in-place over Res allowed)
template <int MODE>
__global__ __launch_bounds__(256) void gemm_bt(const short* __restrict__ A,
                                               const short* __restrict__ Bt,
                                               const void* Res, void* C,
                                               int M, int N, int K) {
  __shared__ __attribute__((aligned(16))) short Alds[128 * 32];
  __shared__ __attribute__((aligned(16))) short Blds[128 * 32];
  int tid = threadIdx.x;
  int lane = tid & 63, w = tid >> 6;
  int wr = w >> 1, wc = w & 1;
  int l15 = lane & 15, lg = lane >> 4;
  int m0 = blockIdx.y * 128, n0 = blockIdx.x * 128;
  f32x4 acc[4][4] = {};
  int arow = tid >> 2, acol = (tid & 3) * 8;
  const short* Ap = A + (size_t)(m0 + arow) * K + acol;
  const short* Bp = Bt + (size_t)(n0 + arow) * K + acol;
  for (int k0 = 0; k0 < K; k0 += 32) {
    int4 a0 = *(const int4*)(Ap + k0);
    int4 a1 = *(const int4*)(Ap + (size_t)64 * K + k0);
    int4 b0 = *(const int4*)(Bp + k0);
    int4 b1 = *(const int4*)(Bp + (size_t)64 * K + k0);
    *(int4*)(Alds + arow * 32 + acol) = a0;
    *(int4*)(Alds + (arow + 64) * 32 + acol) = a1;
    *(int4*)(Blds + arow * 32 + acol) = b0;
    *(int4*)(Blds + (arow + 64) * 32 + acol) = b1;
    __syncthreads();
    bf16x8 af[4], bfr[4];
#pragma unroll
    for (int i = 0; i < 4; ++i) {
      af[i] = *(const bf16x8*)(Alds + (wr * 64 + i * 16 + l15) * 32 + lg * 8);
      bfr[i] = *(const bf16x8*)(Blds + (wc * 64 + i * 16 + l15) * 32 + lg * 8);
    }
#pragma unroll
    for (int mi = 0; mi < 4; ++mi)
#pragma unroll
      for (int ni = 0; ni < 4; ++ni)
        acc[mi][ni] = MFMA16(af[mi], bfr[ni], acc[mi][ni]);
    __syncthreads();
  }
#pragma unroll
  for (int mi = 0; mi < 4; ++mi) {
#pragma unroll
    for (int r = 0; r < 4; ++r) {
      int row = m0 + wr * 64 + mi * 16 + lg * 4 + r;
      size_t base = (size_t)row * N;
#pragma unroll
      for (int ni = 0; ni < 4; ++ni) {
        int col = n0 + wc * 64 + ni * 16 + l15;
        float v = acc[mi][ni][r];
        if (MODE == 0) {
          ((short*)C)[base + col] = f2b(v);
        } else if (MODE == 1) {
          v += ((const float*)Res)[base + col];
          ((float*)C)[base + col] = v;
        } else {
          float rr = b2f(((const short*)Res)[base + col]);
          v = rr / (1.f + __expf(-rr)) * v;
          ((short*)C)[base + col] = f2b(v);
        }
      }
    }
  }
}

// ---------------- RoPE (in-place on Q and K), layout [B*S][H*64], pos = row % 2048
__global__ __launch_bounds__(256) void rope_kernel(short* __restrict__ Q, short* __restrict__ Kb) {
  int idx = blockIdx.x * 256 + threadIdx.x;  // 4096*512 total
  int row = idx >> 9;
  int p = idx & 511;
  int h = p >> 5, i = p & 31;
  int pos = row & 2047;
  float invf = powf(10000.0f, -(float)(2 * i) * (1.0f / 64.0f));
  float ang = (float)pos * invf;
  float sn, cs;
  sincosf(ang, &sn, &cs);
  size_t off = (size_t)row * 1024 + h * 64 + 2 * i;
  {
    float a = b2f(Q[off]), b = b2f(Q[off + 1]);
    Q[off] = f2b(a * cs - b * sn);
    Q[off + 1] = f2b(a * sn + b * cs);
  }
  {
    float a = b2f(Kb[off]), b = b2f(Kb[off + 1]);
    Kb[off] = f2b(a * cs - b * sn);
    Kb[off + 1] = f2b(a * sn + b * cs);
  }
}

// ---------------- Naive attention: one wave per (b,h,q) row; lane = head dim ----
__global__ __launch_bounds__(256) void attn_naive(const short* __restrict__ Q,
                                                  const short* __restrict__ K,
                                                  const short* __restrict__ V,
                                                  short* __restrict__ O) {
  int wid = blockIdx.x * 4 + (threadIdx.x >> 6);  // 0..65535
  int lane = threadIdx.x & 63;
  int q = wid & 2047;
  int h = (wid >> 11) & 15;
  int b = wid >> 15;
  size_t base = (size_t)b * 2048 * 1024 + (size_t)h * 64 + lane;
  float qd = b2f(Q[base + (size_t)q * 1024]);
  float m = -1e30f, l = 0.f, o = 0.f;
  for (int k = 0; k <= q; ++k) {
    size_t off = base + (size_t)k * 1024;
    float s = qd * b2f(K[off]);
    s += __shfl_xor(s, 1, 64);
    s += __shfl_xor(s, 2, 64);
    s += __shfl_xor(s, 4, 64);
    s += __shfl_xor(s, 8, 64);
    s += __shfl_xor(s, 16, 64);
    s += __shfl_xor(s, 32, 64);
    s *= 0.125f;
    float mn = fmaxf(m, s);
    float sc = __expf(m - mn);
    float p = __expf(s - mn);
    l = l * sc + p;
    o = o * sc + p * b2f(V[off]);
    m = mn;
  }
  O[base + (size_t)q * 1024] = f2b(o / l);
}

extern "C" void kernel_launch(void* const* d_in, const int* in_sizes, int n_in,
                              void* d_out, int out_size, void* d_ws, size_t ws_size,
                              hipStream_t stream) {
  const float* xf = (const float*)d_in[0];
  const float* G1f = (const float*)d_in[8];
  const float* G2f = (const float*)d_in[9];
  char* ws = (char*)d_ws;
  const size_t MB = 1048576;
  short* Wslot = (short*)(ws);            // [0,8) recycled for W1,W3,W2
  short* WQb   = (short*)(ws + 8 * MB);   // 2MB each
  short* WKb   = (short*)(ws + 10 * MB);
  short* WVb   = (short*)(ws + 12 * MB);
  short* WOb   = (short*)(ws + 14 * MB);
  short* h     = (short*)(ws + 16 * MB);  // [16,24)
  short* Qb    = (short*)(ws + 24 * MB);  // [24,32)
  short* Kb    = (short*)(ws + 32 * MB);  // [32,40)
  short* Vb    = (short*)(ws + 40 * MB);  // [40,48)
  short* att   = (short*)(ws + 48 * MB);  // [48,56)
  short* w1x   = Qb;                      // [24,56): Q/K/V/att dead by FFN time
  float* x1f   = (float*)d_out;           // f32 trunk lives in d_out (16 MB)
  float* outf  = (float*)d_out;           // final GEMM reads x1f[i], writes outf[i] in-thread

  dim3 blk(256);
  convert_kernel<<<512, blk, 0, stream>>>((const float*)d_in[1], WQb, 1048576);
  convert_kernel<<<512, blk, 0, stream>>>((const float*)d_in[2], WKb, 1048576);
  convert_kernel<<<512, blk, 0, stream>>>((const float*)d_in[3], WVb, 1048576);
  convert_kernel<<<512, blk, 0, stream>>>((const float*)d_in[4], WOb, 1048576);

  rmsnorm_f32<<<4096, blk, 0, stream>>>(xf, G1f, h);
  dim3 g1(8, 32);
  gemm_bt<0><<<g1, blk, 0, stream>>>(h, WQb, nullptr, Qb, 4096, 1024, 1024);
  gemm_bt<0><<<g1, blk, 0, stream>>>(h, WKb, nullptr, Kb, 4096, 1024, 1024);
  gemm_bt<0><<<g1, blk, 0, stream>>>(h, WVb, nullptr, Vb, 4096, 1024, 1024);
  rope_kernel<<<8192, blk, 0, stream>>>(Qb, Kb);
  attn_naive<<<16384, blk, 0, stream>>>(Qb, Kb, Vb, att);
  // x1 = att @ WO^T + x  (f32 residual from original input, f32 out)
  gemm_bt<1><<<g1, blk, 0, stream>>>(att, WOb, xf, x1f, 4096, 1024, 1024);
  rmsnorm_f32<<<4096, blk, 0, stream>>>(x1f, G2f, h);
  dim3 g2(32, 32);
  convert_kernel<<<2048, blk, 0, stream>>>((const float*)d_in[5], Wslot, 4194304);
  gemm_bt<0><<<g2, blk, 0, stream>>>(h, Wslot, nullptr, w1x, 4096, 4096, 1024);
  convert_kernel<<<2048, blk, 0, stream>>>((const float*)d_in[7], Wslot, 4194304);
  gemm_bt<2><<<g2, blk, 0, stream>>>(h, Wslot, w1x, w1x, 4096, 4096, 1024);
  convert_kernel<<<2048, blk, 0, stream>>>((const float*)d_in[6], Wslot, 4194304);
  gemm_bt<1><<<g1, blk, 0, stream>>>(w1x, Wslot, x1f, outf, 4096, 1024, 4096);
}

// Round 5
// 624.841 us; speedup vs baseline: 8.2288x; 8.2288x over previous
//
#include <hip/hip_runtime.h>
#include <stdint.h>

typedef __attribute__((ext_vector_type(8))) short bf16x8;
typedef __attribute__((ext_vector_type(4))) short short4v;
typedef __attribute__((ext_vector_type(4))) float f32x4;

#define MFMA16(a, b, c) __builtin_amdgcn_mfma_f32_16x16x32_bf16((a), (b), (c), 0, 0, 0)

__device__ __forceinline__ float b2f(short s) {
  unsigned u = ((unsigned)(unsigned short)s) << 16;
  return __builtin_bit_cast(float, u);
}
__device__ __forceinline__ short f2b(float f) {
  unsigned u = __builtin_bit_cast(unsigned, f);
  u = (u + 0x7fffu + ((u >> 16) & 1u)) >> 16;
  return (short)u;
}

// -------- convert f32 -> bf16 (8 elems/thread) --------
__global__ __launch_bounds__(256) void convert_kernel(const float* __restrict__ src,
                                                      short* __restrict__ dst, int n) {
  int i = (blockIdx.x * 256 + threadIdx.x) * 8;
  if (i >= n) return;
  f32x4 a = *(const f32x4*)(src + i);
  f32x4 b = *(const f32x4*)(src + i + 4);
  short4v o0, o1;
#pragma unroll
  for (int j = 0; j < 4; ++j) { o0[j] = f2b(a[j]); o1[j] = f2b(b[j]); }
  *(short4v*)(dst + i) = o0;
  *(short4v*)(dst + i + 4) = o1;
}

// -------- RMSNorm: f32 in (x trunk), f32 gamma, bf16 out; one block per row of 1024
__global__ __launch_bounds__(256) void rmsnorm_f32(const float* __restrict__ X,
                                                   const float* __restrict__ G,
                                                   short* __restrict__ O) {
  int row = blockIdx.x;
  int t = threadIdx.x;
  f32x4 v = *(const f32x4*)(X + (size_t)row * 1024 + t * 4);
  float ss = 0.f;
#pragma unroll
  for (int j = 0; j < 4; ++j) ss += v[j] * v[j];
#pragma unroll
  for (int d = 1; d < 64; d <<= 1) ss += __shfl_xor(ss, d, 64);
  __shared__ float red[4];
  if ((t & 63) == 0) red[t >> 6] = ss;
  __syncthreads();
  float tot = red[0] + red[1] + red[2] + red[3];
  float rinv = rsqrtf(tot * (1.0f / 1024.0f) + 1e-5f);
  f32x4 g = *(const f32x4*)(G + t * 4);
  short4v o;
#pragma unroll
  for (int j = 0; j < 4; ++j) o[j] = f2b(v[j] * rinv * g[j]);
  *(short4v*)(O + (size_t)row * 1024 + t * 4) = o;
}

// ---------------- GEMM: C = A[M][K] * Bt[N][K]^T, bf16 A/B, f32 acc
// MODE 0: C = AB (bf16 out)
// MODE 1: C = AB + Resf (f32 res, f32 out) -- Resf may alias C (same-element RAW in-thread)
// MODE 2: C = silu(Res_bf16) * AB (bf16 out, in-place over Res allowed)
template <int MODE>
__global__ __launch_bounds__(256) void gemm_bt(const short* __restrict__ A,
                                               const short* __restrict__ Bt,
                                               const void* Res, void* C,
                                               int M, int N, int K) {
  __shared__ __attribute__((aligned(16))) short Alds[128 * 32];
  __shared__ __attribute__((aligned(16))) short Blds[128 * 32];
  int tid = threadIdx.x;
  int lane = tid & 63, w = tid >> 6;
  int wr = w >> 1, wc = w & 1;
  int l15 = lane & 15, lg = lane >> 4;
  int m0 = blockIdx.y * 128, n0 = blockIdx.x * 128;
  f32x4 acc[4][4] = {};
  int arow = tid >> 2, acol = (tid & 3) * 8;
  const short* Ap = A + (size_t)(m0 + arow) * K + acol;
  const short* Bp = Bt + (size_t)(n0 + arow) * K + acol;
  for (int k0 = 0; k0 < K; k0 += 32) {
    int4 a0 = *(const int4*)(Ap + k0);
    int4 a1 = *(const int4*)(Ap + (size_t)64 * K + k0);
    int4 b0 = *(const int4*)(Bp + k0);
    int4 b1 = *(const int4*)(Bp + (size_t)64 * K + k0);
    *(int4*)(Alds + arow * 32 + acol) = a0;
    *(int4*)(Alds + (arow + 64) * 32 + acol) = a1;
    *(int4*)(Blds + arow * 32 + acol) = b0;
    *(int4*)(Blds + (arow + 64) * 32 + acol) = b1;
    __syncthreads();
    bf16x8 af[4], bfr[4];
#pragma unroll
    for (int i = 0; i < 4; ++i) {
      af[i] = *(const bf16x8*)(Alds + (wr * 64 + i * 16 + l15) * 32 + lg * 8);
      bfr[i] = *(const bf16x8*)(Blds + (wc * 64 + i * 16 + l15) * 32 + lg * 8);
    }
#pragma unroll
    for (int mi = 0; mi < 4; ++mi)
#pragma unroll
      for (int ni = 0; ni < 4; ++ni)
        acc[mi][ni] = MFMA16(af[mi], bfr[ni], acc[mi][ni]);
    __syncthreads();
  }
#pragma unroll
  for (int mi = 0; mi < 4; ++mi) {
#pragma unroll
    for (int r = 0; r < 4; ++r) {
      int row = m0 + wr * 64 + mi * 16 + lg * 4 + r;
      size_t base = (size_t)row * N;
#pragma unroll
      for (int ni = 0; ni < 4; ++ni) {
        int col = n0 + wc * 64 + ni * 16 + l15;
        float v = acc[mi][ni][r];
        if (MODE == 0) {
          ((short*)C)[base + col] = f2b(v);
        } else if (MODE == 1) {
          v += ((const float*)Res)[base + col];
          ((float*)C)[base + col] = v;
        } else {
          float rr = b2f(((const short*)Res)[base + col]);
          v = rr / (1.f + __expf(-rr)) * v;
          ((short*)C)[base + col] = f2b(v);
        }
      }
    }
  }
}

// ---------------- RoPE (in-place on Q and K), layout [B*S][H*64], pos = row % 2048
__global__ __launch_bounds__(256) void rope_kernel(short* __restrict__ Q, short* __restrict__ Kb) {
  int idx = blockIdx.x * 256 + threadIdx.x;  // 4096*512 total
  int row = idx >> 9;
  int p = idx & 511;
  int h = p >> 5, i = p & 31;
  int pos = row & 2047;
  float invf = powf(10000.0f, -(float)(2 * i) * (1.0f / 64.0f));
  float ang = (float)pos * invf;
  float sn, cs;
  sincosf(ang, &sn, &cs);
  size_t off = (size_t)row * 1024 + h * 64 + 2 * i;
  {
    float a = b2f(Q[off]), b = b2f(Q[off + 1]);
    Q[off] = f2b(a * cs - b * sn);
    Q[off + 1] = f2b(a * sn + b * cs);
  }
  {
    float a = b2f(Kb[off]), b = b2f(Kb[off + 1]);
    Kb[off] = f2b(a * cs - b * sn);
    Kb[off + 1] = f2b(a * sn + b * cs);
  }
}

// ---------------- Flash attention: grid (S/64, B*H), 4 waves, 16 q/wave, KV chunk 32
__global__ __launch_bounds__(256) void attn_kernel(const short* __restrict__ Q,
                                                   const short* __restrict__ K,
                                                   const short* __restrict__ V,
                                                   short* __restrict__ O) {
  __shared__ __attribute__((aligned(16))) short Klds[32 * 64];
  __shared__ __attribute__((aligned(16))) short Vtlds[64 * 32];
  __shared__ __attribute__((aligned(16))) short Ptlds[4][32 * 20];  // per-wave P^T, padded
  int bh = blockIdx.y;
  size_t rowbase = (size_t)(bh >> 4) * 2048 * 1024 + (size_t)(bh & 15) * 64;
  int q0 = blockIdx.x * 64;
  int tid = threadIdx.x;
  int w = tid >> 6, lane = tid & 63;
  int l15 = lane & 15, lg = lane >> 4;
  int qbase = q0 + w * 16;
  bf16x8 qf[2];
  {
    const short* qp = Q + rowbase + (size_t)(qbase + l15) * 1024 + lg * 8;
    qf[0] = *(const bf16x8*)qp;
    qf[1] = *(const bf16x8*)(qp + 32);
  }
  f32x4 oacc[4] = {};
  float mrun[4], lrun[4];
#pragma unroll
  for (int r = 0; r < 4; ++r) { mrun[r] = -1e9f; lrun[r] = 0.f; }
  int nchunk = (q0 + 64) >> 5;
  int srow = tid >> 3, scol8 = tid & 7;
  const short* Kg = K + rowbase + (size_t)srow * 1024 + scol8 * 8;
  const short* Vg = V + rowbase + (size_t)srow * 1024 + scol8 * 8;
  for (int kt = 0; kt < nchunk; ++kt) {
    size_t koff = (size_t)kt * 32 * 1024;
    // stage K chunk [32][64] with XOR swizzle (G4 fix for 128B rows)
    int4 kv = *(const int4*)(Kg + koff);
    int kbyte = (srow * 128 + scol8 * 16) ^ ((srow & 7) << 4);
    *(int4*)((char*)Klds + kbyte) = kv;
    // stage V^T [64][32] with XOR swizzle
    bf16x8 vv = *(const bf16x8*)(Vg + koff);
#pragma unroll
    for (int j = 0; j < 8; ++j) {
      int d = scol8 * 8 + j;
      int vbyte = (d * 64 + srow * 2) ^ ((d & 3) << 4);
      *(short*)((char*)Vtlds + vbyte) = vv[j];
    }
    __syncthreads();
    int kstart = kt * 32;
    if (kstart <= qbase + 15) {
      f32x4 s[2] = {};
#pragma unroll
      for (int g = 0; g < 2; ++g) {
#pragma unroll
        for (int t = 0; t < 2; ++t) {
          int rowk = g * 16 + l15;
          int byte = (rowk * 128 + t * 64 + lg * 16) ^ ((rowk & 7) << 4);
          bf16x8 kf = *(const bf16x8*)((char*)Klds + byte);
          s[g] = MFMA16(qf[t], kf, s[g]);
        }
      }
      float pm[2][4];
#pragma unroll
      for (int r = 0; r < 4; ++r) {
        int qg = qbase + lg * 4 + r;
#pragma unroll
        for (int g = 0; g < 2; ++g) {
          float v = s[g][r] * 0.125f;
          int kg = kstart + g * 16 + l15;
          pm[g][r] = (kg > qg) ? -1e9f : v;
        }
        float mx = fmaxf(pm[0][r], pm[1][r]);
        mx = fmaxf(mx, __shfl_xor(mx, 1, 64));
        mx = fmaxf(mx, __shfl_xor(mx, 2, 64));
        mx = fmaxf(mx, __shfl_xor(mx, 4, 64));
        mx = fmaxf(mx, __shfl_xor(mx, 8, 64));
        float mnew = fmaxf(mrun[r], mx);
        float scale = __expf(mrun[r] - mnew);
        mrun[r] = mnew;
        float rs = 0.f;
#pragma unroll
        for (int g = 0; g < 2; ++g) {
          float pp = __expf(pm[g][r] - mnew);
          pm[g][r] = pp;
          rs += pp;
        }
        rs += __shfl_xor(rs, 1, 64);
        rs += __shfl_xor(rs, 2, 64);
        rs += __shfl_xor(rs, 4, 64);
        rs += __shfl_xor(rs, 8, 64);
        lrun[r] = lrun[r] * scale + rs;
#pragma unroll
        for (int t = 0; t < 4; ++t) oacc[t][r] *= scale;
      }
      // P (C-layout) -> P^T in LDS -> A-frag layout for PV
      short* pt = Ptlds[w];
#pragma unroll
      for (int g = 0; g < 2; ++g) {
        short4v pk;
#pragma unroll
        for (int r = 0; r < 4; ++r) pk[r] = f2b(pm[g][r]);
        *(short4v*)(pt + (g * 16 + l15) * 20 + lg * 4) = pk;
      }
      bf16x8 pa;
#pragma unroll
      for (int j = 0; j < 8; ++j) pa[j] = pt[(lg * 8 + j) * 20 + l15];
#pragma unroll
      for (int t = 0; t < 4; ++t) {
        int d = t * 16 + l15;
        int byte = (d * 64 + lg * 16) ^ ((d & 3) << 4);
        bf16x8 vf = *(const bf16x8*)((char*)Vtlds + byte);
        oacc[t] = MFMA16(pa, vf, oacc[t]);
      }
    }
    __syncthreads();
  }
#pragma unroll
  for (int t = 0; t < 4; ++t) {
#pragma unroll
    for (int r = 0; r < 4; ++r) {
      int row = qbase + lg * 4 + r;
      float denom = fmaxf(lrun[r], 1e-20f);
      O[rowbase + (size_t)row * 1024 + t * 16 + l15] = f2b(oacc[t][r] / denom);
    }
  }
}

extern "C" void kernel_launch(void* const* d_in, const int* in_sizes, int n_in,
                              void* d_out, int out_size, void* d_ws, size_t ws_size,
                              hipStream_t stream) {
  const float* xf = (const float*)d_in[0];
  const float* G1f = (const float*)d_in[8];
  const float* G2f = (const float*)d_in[9];
  char* ws = (char*)d_ws;
  const size_t MB = 1048576;
  short* Wslot = (short*)(ws);            // [0,8) recycled for W1,W3,W2
  short* WQb   = (short*)(ws + 8 * MB);   // 2MB each
  short* WKb   = (short*)(ws + 10 * MB);
  short* WVb   = (short*)(ws + 12 * MB);
  short* WOb   = (short*)(ws + 14 * MB);
  short* h     = (short*)(ws + 16 * MB);  // [16,24)
  short* Qb    = (short*)(ws + 24 * MB);  // [24,32)
  short* Kb    = (short*)(ws + 32 * MB);  // [32,40)
  short* Vb    = (short*)(ws + 40 * MB);  // [40,48)
  short* att   = (short*)(ws + 48 * MB);  // [48,56)
  short* w1x   = Qb;                      // [24,56): Q/K/V/att dead by FFN time
  float* x1f   = (float*)d_out;           // f32 trunk lives in d_out (16 MB)
  float* outf  = (float*)d_out;           // final GEMM reads x1f[i], writes outf[i] in-thread

  dim3 blk(256);
  convert_kernel<<<512, blk, 0, stream>>>((const float*)d_in[1], WQb, 1048576);
  convert_kernel<<<512, blk, 0, stream>>>((const float*)d_in[2], WKb, 1048576);
  convert_kernel<<<512, blk, 0, stream>>>((const float*)d_in[3], WVb, 1048576);
  convert_kernel<<<512, blk, 0, stream>>>((const float*)d_in[4], WOb, 1048576);

  rmsnorm_f32<<<4096, blk, 0, stream>>>(xf, G1f, h);
  dim3 g1(8, 32);
  gemm_bt<0><<<g1, blk, 0, stream>>>(h, WQb, nullptr, Qb, 4096, 1024, 1024);
  gemm_bt<0><<<g1, blk, 0, stream>>>(h, WKb, nullptr, Kb, 4096, 1024, 1024);
  gemm_bt<0><<<g1, blk, 0, stream>>>(h, WVb, nullptr, Vb, 4096, 1024, 1024);
  rope_kernel<<<8192, blk, 0, stream>>>(Qb, Kb);
  dim3 ga(32, 32);
  attn_kernel<<<ga, blk, 0, stream>>>(Qb, Kb, Vb, att);
  // x1 = att @ WO^T + x  (f32 residual from original input, f32 out)
  gemm_bt<1><<<g1, blk, 0, stream>>>(att, WOb, xf, x1f, 4096, 1024, 1024);
  rmsnorm_f32<<<4096, blk, 0, stream>>>(x1f, G2f, h);
  dim3 g2(32, 32);
  convert_kernel<<<2048, blk, 0, stream>>>((const float*)d_in[5], Wslot, 4194304);
  gemm_bt<0><<<g2, blk, 0, stream>>>(h, Wslot, nullptr, w1x, 4096, 4096, 1024);
  convert_kernel<<<2048, blk, 0, stream>>>((const float*)d_in[7], Wslot, 4194304);
  gemm_bt<2><<<g2, blk, 0, stream>>>(h, Wslot, w1x, w1x, 4096, 4096, 1024);
  convert_kernel<<<2048, blk, 0, stream>>>((const float*)d_in[6], Wslot, 4194304);
  gemm_bt<1><<<g1, blk, 0, stream>>>(w1x, Wslot, x1f, outf, 4096, 1024, 4096);
}

// Round 6
// 597.736 us; speedup vs baseline: 8.6019x; 1.0453x over previous
//
#include <hip/hip_runtime.h>
#include <stdint.h>

typedef __attribute__((ext_vector_type(8))) short bf16x8;
typedef __attribute__((ext_vector_type(4))) short short4v;
typedef __attribute__((ext_vector_type(4))) float f32x4;

#define MFMA16(a, b, c) __builtin_amdgcn_mfma_f32_16x16x32_bf16((a), (b), (c), 0, 0, 0)

__device__ __forceinline__ float b2f(short s) {
  unsigned u = ((unsigned)(unsigned short)s) << 16;
  return __builtin_bit_cast(float, u);
}
__device__ __forceinline__ short f2b(float f) {
  unsigned u = __builtin_bit_cast(unsigned, f);
  u = (u + 0x7fffu + ((u >> 16) & 1u)) >> 16;
  return (short)u;
}

// async global->LDS, 16B per lane; lds dest must be wave-uniform base (HW adds lane*16)
__device__ __forceinline__ void gl_lds16(const short* g, short* l) {
  __builtin_amdgcn_global_load_lds((const __attribute__((address_space(1))) void*)g,
                                   (__attribute__((address_space(3))) void*)l, 16, 0, 0);
}

// -------- convert f32 -> bf16 (8 elems/thread) --------
__global__ __launch_bounds__(256) void convert_kernel(const float* __restrict__ src,
                                                      short* __restrict__ dst, int n) {
  int i = (blockIdx.x * 256 + threadIdx.x) * 8;
  if (i >= n) return;
  f32x4 a = *(const f32x4*)(src + i);
  f32x4 b = *(const f32x4*)(src + i + 4);
  short4v o0, o1;
#pragma unroll
  for (int j = 0; j < 4; ++j) { o0[j] = f2b(a[j]); o1[j] = f2b(b[j]); }
  *(short4v*)(dst + i) = o0;
  *(short4v*)(dst + i + 4) = o1;
}

// -------- RMSNorm: f32 in, f32 gamma, bf16 out; one block per row of 1024 --------
__global__ __launch_bounds__(256) void rmsnorm_f32(const float* __restrict__ X,
                                                   const float* __restrict__ G,
                                                   short* __restrict__ O) {
  int row = blockIdx.x;
  int t = threadIdx.x;
  f32x4 v = *(const f32x4*)(X + (size_t)row * 1024 + t * 4);
  float ss = 0.f;
#pragma unroll
  for (int j = 0; j < 4; ++j) ss += v[j] * v[j];
#pragma unroll
  for (int d = 1; d < 64; d <<= 1) ss += __shfl_xor(ss, d, 64);
  __shared__ float red[4];
  if ((t & 63) == 0) red[t >> 6] = ss;
  __syncthreads();
  float tot = red[0] + red[1] + red[2] + red[3];
  float rinv = rsqrtf(tot * (1.0f / 1024.0f) + 1e-5f);
  f32x4 g = *(const f32x4*)(G + t * 4);
  short4v o;
#pragma unroll
  for (int j = 0; j < 4; ++j) o[j] = f2b(v[j] * rinv * g[j]);
  *(short4v*)(O + (size_t)row * 1024 + t * 4) = o;
}

// ---------------- GEMM: C = A[M][K] * Bt[N][K]^T, bf16 A/B, f32 acc, gl_lds staging
// MODE 0: C = AB (bf16 out)
// MODE 1: C = AB + Resf (f32 res, f32 out; Res may alias C: same-elem in-thread RAW)
// MODE 2: C = silu(Res_bf16) * AB (bf16 out, in-place over Res allowed)
// MODE 3: QKV-split: N must be 1024; col segment n0>>10 picks C/C1/C2
template <int MODE>
__global__ __launch_bounds__(256) void gemm_bt(const short* __restrict__ A,
                                               const short* __restrict__ Bt,
                                               const void* Res, void* C,
                                               void* C1, void* C2,
                                               int M, int N, int K) {
  __shared__ __attribute__((aligned(16))) short Alds[128 * 32];
  __shared__ __attribute__((aligned(16))) short Blds[128 * 32];
  int tid = threadIdx.x;
  int lane = tid & 63, w = tid >> 6;
  int wr = w >> 1, wc = w & 1;
  int l15 = lane & 15, lg = lane >> 4;
  int m0 = blockIdx.y * 128, n0 = blockIdx.x * 128;
  void* Cw = C;
  int ncol0 = n0;
  if (MODE == 3) {
    int seg = n0 >> 10;
    Cw = (seg == 0) ? C : (seg == 1) ? C1 : C2;
    ncol0 = n0 & 1023;
  }
  f32x4 acc[4][4] = {};
  int arow = tid >> 2, acol = (tid & 3) * 8;  // LDS byte off = 16*tid (linear in tid)
  const short* Ap = A + (size_t)(m0 + arow) * K + acol;
  const short* Bp = Bt + (size_t)(n0 + arow) * K + acol;
  int wb = w * 512;  // wave's 1KB LDS slot (shorts)
  for (int k0 = 0; k0 < K; k0 += 32) {
    gl_lds16(Ap + k0, Alds + wb);
    gl_lds16(Ap + (size_t)64 * K + k0, Alds + 2048 + wb);
    gl_lds16(Bp + k0, Blds + wb);
    gl_lds16(Bp + (size_t)64 * K + k0, Blds + 2048 + wb);
    __syncthreads();  // compiler drains vmcnt before s_barrier
    bf16x8 af[4], bfr[4];
#pragma unroll
    for (int i = 0; i < 4; ++i) {
      af[i] = *(const bf16x8*)(Alds + (wr * 64 + i * 16 + l15) * 32 + lg * 8);
      bfr[i] = *(const bf16x8*)(Blds + (wc * 64 + i * 16 + l15) * 32 + lg * 8);
    }
#pragma unroll
    for (int mi = 0; mi < 4; ++mi)
#pragma unroll
      for (int ni = 0; ni < 4; ++ni)
        acc[mi][ni] = MFMA16(af[mi], bfr[ni], acc[mi][ni]);
    __syncthreads();
  }
#pragma unroll
  for (int mi = 0; mi < 4; ++mi) {
#pragma unroll
    for (int r = 0; r < 4; ++r) {
      int row = m0 + wr * 64 + mi * 16 + lg * 4 + r;
      size_t base = (size_t)row * N;
#pragma unroll
      for (int ni = 0; ni < 4; ++ni) {
        int col = ncol0 + wc * 64 + ni * 16 + l15;
        float v = acc[mi][ni][r];
        if (MODE == 1) {
          v += ((const float*)Res)[base + col];
          ((float*)Cw)[base + col] = v;
        } else if (MODE == 2) {
          float rr = b2f(((const short*)Res)[base + col]);
          v = rr / (1.f + __expf(-rr)) * v;
          ((short*)Cw)[base + col] = f2b(v);
        } else {
          ((short*)Cw)[base + col] = f2b(v);
        }
      }
    }
  }
}

// ---------------- RoPE (in-place on Q and K), layout [B*S][H*64], pos = row % 2048
__global__ __launch_bounds__(256) void rope_kernel(short* __restrict__ Q, short* __restrict__ Kb) {
  int idx = blockIdx.x * 256 + threadIdx.x;  // 4096*512 total
  int row = idx >> 9;
  int p = idx & 511;
  int h = p >> 5, i = p & 31;
  int pos = row & 2047;
  float invf = powf(10000.0f, -(float)(2 * i) * (1.0f / 64.0f));
  float ang = (float)pos * invf;
  float sn, cs;
  sincosf(ang, &sn, &cs);
  size_t off = (size_t)row * 1024 + h * 64 + 2 * i;
  {
    float a = b2f(Q[off]), b = b2f(Q[off + 1]);
    Q[off] = f2b(a * cs - b * sn);
    Q[off + 1] = f2b(a * sn + b * cs);
  }
  {
    float a = b2f(Kb[off]), b = b2f(Kb[off + 1]);
    Kb[off] = f2b(a * cs - b * sn);
    Kb[off + 1] = f2b(a * sn + b * cs);
  }
}

// ---------------- V transpose: V[B*S][H*64] -> Vt[bh][64][2048] ----------------
__global__ __launch_bounds__(256) void vtranspose(const short* __restrict__ V,
                                                  short* __restrict__ Vt) {
  __shared__ short T[64 * 72];
  int bh = blockIdx.y;
  int s0 = blockIdx.x * 64;
  int t = threadIdx.x;
  int r = t >> 2, cq = t & 3;
  const short* src = V + (size_t)((bh >> 4) * 2048 + s0 + r) * 1024 + (bh & 15) * 64 + cq * 16;
  *(int4*)(T + r * 72 + cq * 16) = *(const int4*)src;
  *(int4*)(T + r * 72 + cq * 16 + 8) = *(const int4*)(src + 8);
  __syncthreads();
  int d = t >> 2, sq = t & 3;
  short* dst = Vt + (size_t)bh * 131072 + (size_t)d * 2048 + s0 + sq * 16;
#pragma unroll
  for (int q = 0; q < 4; ++q) {
    short4v o;
#pragma unroll
    for (int j = 0; j < 4; ++j) o[j] = T[(sq * 16 + q * 4 + j) * 72 + d];
    *(short4v*)(dst + q * 4) = o;
  }
}

// ---------------- Flash attention v2: barrier-free, per-wave 16 queries ----------
// grid 1024 blocks x 256 thr; bh = bx>>5; qbase = (bx&31)*64 + w*16; KV from L2/L3.
__global__ __launch_bounds__(256) void attn2(const short* __restrict__ Q,
                                             const short* __restrict__ K,
                                             const short* __restrict__ Vt,
                                             short* __restrict__ O) {
  __shared__ __attribute__((aligned(16))) short Ptlds[4][32 * 20];
  int bx = blockIdx.x;
  int bh = bx >> 5;
  int tid = threadIdx.x;
  int w = tid >> 6, lane = tid & 63;
  int l15 = lane & 15, lg = lane >> 4;
  int qbase = (bx & 31) * 64 + w * 16;
  size_t rowbase = (size_t)(bh >> 4) * 2048 * 1024 + (size_t)(bh & 15) * 64;
  const short* vtb = Vt + (size_t)bh * 131072;
  bf16x8 qf[2];
  {
    const short* qp = Q + rowbase + (size_t)(qbase + l15) * 1024 + lg * 8;
    qf[0] = *(const bf16x8*)qp;
    qf[1] = *(const bf16x8*)(qp + 32);
  }
  f32x4 oacc[4] = {};
  float mrun[4], lrun[4];
#pragma unroll
  for (int r = 0; r < 4; ++r) { mrun[r] = -1e9f; lrun[r] = 0.f; }
  int nchunk = (qbase + 47) >> 5;  // kstart <= qbase always
  short* pt = Ptlds[w];
  const short* Kb0 = K + rowbase;
  for (int kt = 0; kt < nchunk; ++kt) {
    int kstart = kt * 32;
    f32x4 s[2] = {};
#pragma unroll
    for (int g = 0; g < 2; ++g) {
      const short* kp = Kb0 + (size_t)(kstart + g * 16 + l15) * 1024 + lg * 8;
      bf16x8 k0 = *(const bf16x8*)kp;
      bf16x8 k1 = *(const bf16x8*)(kp + 32);
      s[g] = MFMA16(qf[0], k0, s[g]);
      s[g] = MFMA16(qf[1], k1, s[g]);
    }
    float pm[2][4];
#pragma unroll
    for (int r = 0; r < 4; ++r) {
      int qg = qbase + lg * 4 + r;
#pragma unroll
      for (int g = 0; g < 2; ++g) {
        float v = s[g][r] * 0.125f;
        int kg = kstart + g * 16 + l15;
        pm[g][r] = (kg > qg) ? -1e9f : v;
      }
      float mx = fmaxf(pm[0][r], pm[1][r]);
      mx = fmaxf(mx, __shfl_xor(mx, 1, 64));
      mx = fmaxf(mx, __shfl_xor(mx, 2, 64));
      mx = fmaxf(mx, __shfl_xor(mx, 4, 64));
      mx = fmaxf(mx, __shfl_xor(mx, 8, 64));
      float mnew = fmaxf(mrun[r], mx);
      float scale = __expf(mrun[r] - mnew);
      mrun[r] = mnew;
      float rs = 0.f;
#pragma unroll
      for (int g = 0; g < 2; ++g) {
        float pp = __expf(pm[g][r] - mnew);
        pm[g][r] = pp;
        rs += pp;
      }
      rs += __shfl_xor(rs, 1, 64);
      rs += __shfl_xor(rs, 2, 64);
      rs += __shfl_xor(rs, 4, 64);
      rs += __shfl_xor(rs, 8, 64);
      lrun[r] = lrun[r] * scale + rs;
#pragma unroll
      for (int t = 0; t < 4; ++t) oacc[t][r] *= scale;
    }
    // P (C-layout) -> P^T via per-wave LDS (no barrier: within-wave lockstep)
#pragma unroll
    for (int g = 0; g < 2; ++g) {
      short4v pk;
#pragma unroll
      for (int r = 0; r < 4; ++r) pk[r] = f2b(pm[g][r]);
      *(short4v*)(pt + (g * 16 + l15) * 20 + lg * 4) = pk;
    }
    bf16x8 pa;
#pragma unroll
    for (int j = 0; j < 8; ++j) pa[j] = pt[(lg * 8 + j) * 20 + l15];
#pragma unroll
    for (int t = 0; t < 4; ++t) {
      bf16x8 vf = *(const bf16x8*)(vtb + (size_t)(t * 16 + l15) * 2048 + kstart + lg * 8);
      oacc[t] = MFMA16(pa, vf, oacc[t]);
    }
  }
#pragma unroll
  for (int t = 0; t < 4; ++t) {
#pragma unroll
    for (int r = 0; r < 4; ++r) {
      int row = qbase + lg * 4 + r;
      float denom = fmaxf(lrun[r], 1e-20f);
      O[rowbase + (size_t)row * 1024 + t * 16 + l15] = f2b(oacc[t][r] / denom);
    }
  }
}

extern "C" void kernel_launch(void* const* d_in, const int* in_sizes, int n_in,
                              void* d_out, int out_size, void* d_ws, size_t ws_size,
                              hipStream_t stream) {
  const float* xf = (const float*)d_in[0];
  const float* G1f = (const float*)d_in[8];
  const float* G2f = (const float*)d_in[9];
  char* ws = (char*)d_ws;
  const size_t MB = 1048576;
  short* Wslot = (short*)(ws);            // [0,8): WOb early, then W1/W3/W2
  short* WOb   = (short*)(ws);            //   (dead before first Wslot convert)
  short* Wcat  = (short*)(ws + 8 * MB);   // [8,14): fused QKV weights [3072][1024]
  short* Vt    = (short*)(ws + 8 * MB);   // [8,16): V^T (after Wcat dead)
  short* h     = (short*)(ws + 16 * MB);  // [16,24)
  short* Qb    = (short*)(ws + 24 * MB);  // [24,32)
  short* Kb    = (short*)(ws + 32 * MB);  // [32,40)
  short* Vb    = (short*)(ws + 40 * MB);  // [40,48)
  short* att   = (short*)(ws + 48 * MB);  // [48,56)
  short* w1x   = Qb;                      // [24,56): Q/K/V/att dead by FFN time
  float* x1f   = (float*)d_out;           // f32 trunk lives in d_out
  float* outf  = (float*)d_out;

  dim3 blk(256);
  convert_kernel<<<512, blk, 0, stream>>>((const float*)d_in[1], Wcat, 1048576);
  convert_kernel<<<512, blk, 0, stream>>>((const float*)d_in[2], Wcat + 1048576, 1048576);
  convert_kernel<<<512, blk, 0, stream>>>((const float*)d_in[3], Wcat + 2097152, 1048576);
  convert_kernel<<<512, blk, 0, stream>>>((const float*)d_in[4], WOb, 1048576);

  rmsnorm_f32<<<4096, blk, 0, stream>>>(xf, G1f, h);
  dim3 gqkv(24, 32);
  gemm_bt<3><<<gqkv, blk, 0, stream>>>(h, Wcat, nullptr, Qb, Kb, Vb, 4096, 1024, 1024);
  rope_kernel<<<8192, blk, 0, stream>>>(Qb, Kb);
  dim3 gvt(32, 32);
  vtranspose<<<gvt, blk, 0, stream>>>(Vb, Vt);
  attn2<<<1024, blk, 0, stream>>>(Qb, Kb, Vt, att);
  dim3 g1(8, 32);
  gemm_bt<1><<<g1, blk, 0, stream>>>(att, WOb, xf, x1f, nullptr, nullptr, 4096, 1024, 1024);
  rmsnorm_f32<<<4096, blk, 0, stream>>>(x1f, G2f, h);
  dim3 g2(32, 32);
  convert_kernel<<<2048, blk, 0, stream>>>((const float*)d_in[5], Wslot, 4194304);
  gemm_bt<0><<<g2, blk, 0, stream>>>(h, Wslot, nullptr, w1x, nullptr, nullptr, 4096, 4096, 1024);
  convert_kernel<<<2048, blk, 0, stream>>>((const float*)d_in[7], Wslot, 4194304);
  gemm_bt<2><<<g2, blk, 0, stream>>>(h, Wslot, w1x, w1x, nullptr, nullptr, 4096, 4096, 1024);
  convert_kernel<<<2048, blk, 0, stream>>>((const float*)d_in[6], Wslot, 4194304);
  gemm_bt<1><<<g1, blk, 0, stream>>>(w1x, Wslot, x1f, outf, nullptr, nullptr, 4096, 1024, 4096);
}

// Round 7
// 483.991 us; speedup vs baseline: 10.6235x; 1.2350x over previous
//
#include <hip/hip_runtime.h>
#include <stdint.h>

typedef __attribute__((ext_vector_type(8))) short bf16x8;
typedef __attribute__((ext_vector_type(4))) short short4v;
typedef __attribute__((ext_vector_type(4))) float f32x4;

#define MFMA16(a, b, c) __builtin_amdgcn_mfma_f32_16x16x32_bf16((a), (b), (c), 0, 0, 0)

__device__ __forceinline__ float b2f(short s) {
  unsigned u = ((unsigned)(unsigned short)s) << 16;
  return __builtin_bit_cast(float, u);
}
__device__ __forceinline__ short f2b(float f) {
  unsigned u = __builtin_bit_cast(unsigned, f);
  u = (u + 0x7fffu + ((u >> 16) & 1u)) >> 16;
  return (short)u;
}

// async global->LDS, 16B per lane; lds dest is wave-uniform base (HW adds lane*16)
__device__ __forceinline__ void gl_lds16(const short* g, short* l) {
  __builtin_amdgcn_global_load_lds((const __attribute__((address_space(1))) void*)g,
                                   (__attribute__((address_space(3))) void*)l, 16, 0, 0);
}

// -------- convert f32 -> bf16 (8 elems/thread) --------
__global__ __launch_bounds__(256) void convert_kernel(const float* __restrict__ src,
                                                      short* __restrict__ dst, int n) {
  int i = (blockIdx.x * 256 + threadIdx.x) * 8;
  if (i >= n) return;
  f32x4 a = *(const f32x4*)(src + i);
  f32x4 b = *(const f32x4*)(src + i + 4);
  short4v o0, o1;
#pragma unroll
  for (int j = 0; j < 4; ++j) { o0[j] = f2b(a[j]); o1[j] = f2b(b[j]); }
  *(short4v*)(dst + i) = o0;
  *(short4v*)(dst + i + 4) = o1;
}

// -------- RMSNorm: f32 in, f32 gamma, bf16 out; one block per row of 1024 --------
__global__ __launch_bounds__(256) void rmsnorm_f32(const float* __restrict__ X,
                                                   const float* __restrict__ G,
                                                   short* __restrict__ O) {
  int row = blockIdx.x;
  int t = threadIdx.x;
  f32x4 v = *(const f32x4*)(X + (size_t)row * 1024 + t * 4);
  float ss = 0.f;
#pragma unroll
  for (int j = 0; j < 4; ++j) ss += v[j] * v[j];
#pragma unroll
  for (int d = 1; d < 64; d <<= 1) ss += __shfl_xor(ss, d, 64);
  __shared__ float red[4];
  if ((t & 63) == 0) red[t >> 6] = ss;
  __syncthreads();
  float tot = red[0] + red[1] + red[2] + red[3];
  float rinv = rsqrtf(tot * (1.0f / 1024.0f) + 1e-5f);
  f32x4 g = *(const f32x4*)(G + t * 4);
  short4v o;
#pragma unroll
  for (int j = 0; j < 4; ++j) o[j] = f2b(v[j] * rinv * g[j]);
  *(short4v*)(O + (size_t)row * 1024 + t * 4) = o;
}

// ---------------- GEMM (256 thr, 4 waves 2x2, 128x128, BK=32, gl_lds staging)
// MODE 0: C = AB (bf16 out)
// MODE 2: C = silu(Res_bf16) * AB (bf16 out, in-place over Res allowed)
// MODE 3: QKV-split: N=1024 segments -> C/C1/C2
template <int MODE>
__global__ __launch_bounds__(256) void gemm_bt(const short* __restrict__ A,
                                               const short* __restrict__ Bt,
                                               const void* Res, void* C,
                                               void* C1, void* C2,
                                               int M, int N, int K) {
  __shared__ __attribute__((aligned(16))) short Alds[128 * 32];
  __shared__ __attribute__((aligned(16))) short Blds[128 * 32];
  int tid = threadIdx.x;
  int lane = tid & 63, w = tid >> 6;
  int wr = w >> 1, wc = w & 1;
  int l15 = lane & 15, lg = lane >> 4;
  int m0 = blockIdx.y * 128, n0 = blockIdx.x * 128;
  void* Cw = C;
  int ncol0 = n0;
  if (MODE == 3) {
    int seg = n0 >> 10;
    Cw = (seg == 0) ? C : (seg == 1) ? C1 : C2;
    ncol0 = n0 & 1023;
  }
  f32x4 acc[4][4] = {};
  int arow = tid >> 2, acol = (tid & 3) * 8;  // LDS byte off = 16*tid (linear)
  const short* Ap = A + (size_t)(m0 + arow) * K + acol;
  const short* Bp = Bt + (size_t)(n0 + arow) * K + acol;
  int wb = w * 512;
  for (int k0 = 0; k0 < K; k0 += 32) {
    gl_lds16(Ap + k0, Alds + wb);
    gl_lds16(Ap + (size_t)64 * K + k0, Alds + 2048 + wb);
    gl_lds16(Bp + k0, Blds + wb);
    gl_lds16(Bp + (size_t)64 * K + k0, Blds + 2048 + wb);
    __syncthreads();
    bf16x8 af[4], bfr[4];
#pragma unroll
    for (int i = 0; i < 4; ++i) {
      af[i] = *(const bf16x8*)(Alds + (wr * 64 + i * 16 + l15) * 32 + lg * 8);
      bfr[i] = *(const bf16x8*)(Blds + (wc * 64 + i * 16 + l15) * 32 + lg * 8);
    }
#pragma unroll
    for (int mi = 0; mi < 4; ++mi)
#pragma unroll
      for (int ni = 0; ni < 4; ++ni)
        acc[mi][ni] = MFMA16(af[mi], bfr[ni], acc[mi][ni]);
    __syncthreads();
  }
#pragma unroll
  for (int mi = 0; mi < 4; ++mi) {
#pragma unroll
    for (int r = 0; r < 4; ++r) {
      int row = m0 + wr * 64 + mi * 16 + lg * 4 + r;
      size_t base = (size_t)row * N;
#pragma unroll
      for (int ni = 0; ni < 4; ++ni) {
        int col = ncol0 + wc * 64 + ni * 16 + l15;
        float v = acc[mi][ni][r];
        if (MODE == 2) {
          float rr = b2f(((const short*)Res)[base + col]);
          v = rr / (1.f + __expf(-rr)) * v;
          ((short*)Cw)[base + col] = f2b(v);
        } else {
          ((short*)Cw)[base + col] = f2b(v);
        }
      }
    }
  }
}

// ---------------- GEMM wide: 512 thr, 8 waves 2x4, 128x128, C = AB + Resf (f32 out)
// For the 1-block/CU shapes (WO, W2): 2 waves/SIMD restores latency hiding.
__global__ __launch_bounds__(512) void gemm_wide(const short* __restrict__ A,
                                                 const short* __restrict__ Bt,
                                                 const float* Res, float* C,
                                                 int M, int N, int K) {
  __shared__ __attribute__((aligned(16))) short Alds[128 * 32];
  __shared__ __attribute__((aligned(16))) short Blds[128 * 32];
  int tid = threadIdx.x;
  int lane = tid & 63, w = tid >> 6;       // 8 waves
  int wr = w >> 2, wc = w & 3;             // 2 x 4
  int l15 = lane & 15, lg = lane >> 4;
  int m0 = blockIdx.y * 128, n0 = blockIdx.x * 128;
  f32x4 acc[4][2] = {};
  int arow = tid >> 2, acol = (tid & 3) * 8;  // 512 thr cover 128x32: byte = 16*tid
  const short* Ap = A + (size_t)(m0 + arow) * K + acol;
  const short* Bp = Bt + (size_t)(n0 + arow) * K + acol;
  int wb = w * 512;
  for (int k0 = 0; k0 < K; k0 += 32) {
    gl_lds16(Ap + k0, Alds + wb);
    gl_lds16(Bp + k0, Blds + wb);
    __syncthreads();
    bf16x8 af[4], bfr[2];
#pragma unroll
    for (int i = 0; i < 4; ++i)
      af[i] = *(const bf16x8*)(Alds + (wr * 64 + i * 16 + l15) * 32 + lg * 8);
#pragma unroll
    for (int i = 0; i < 2; ++i)
      bfr[i] = *(const bf16x8*)(Blds + (wc * 32 + i * 16 + l15) * 32 + lg * 8);
#pragma unroll
    for (int mi = 0; mi < 4; ++mi)
#pragma unroll
      for (int ni = 0; ni < 2; ++ni)
        acc[mi][ni] = MFMA16(af[mi], bfr[ni], acc[mi][ni]);
    __syncthreads();
  }
#pragma unroll
  for (int mi = 0; mi < 4; ++mi) {
#pragma unroll
    for (int r = 0; r < 4; ++r) {
      int row = m0 + wr * 64 + mi * 16 + lg * 4 + r;
      size_t base = (size_t)row * N;
#pragma unroll
      for (int ni = 0; ni < 2; ++ni) {
        int col = n0 + wc * 32 + ni * 16 + l15;
        C[base + col] = acc[mi][ni][r] + Res[base + col];
      }
    }
  }
}

// ---------------- RoPE (in-place on Q and K), layout [B*S][H*64], pos = row % 2048
__global__ __launch_bounds__(256) void rope_kernel(short* __restrict__ Q, short* __restrict__ Kb) {
  int idx = blockIdx.x * 256 + threadIdx.x;
  int row = idx >> 9;
  int p = idx & 511;
  int h = p >> 5, i = p & 31;
  int pos = row & 2047;
  float invf = powf(10000.0f, -(float)(2 * i) * (1.0f / 64.0f));
  float ang = (float)pos * invf;
  float sn, cs;
  sincosf(ang, &sn, &cs);
  size_t off = (size_t)row * 1024 + h * 64 + 2 * i;
  {
    float a = b2f(Q[off]), b = b2f(Q[off + 1]);
    Q[off] = f2b(a * cs - b * sn);
    Q[off + 1] = f2b(a * sn + b * cs);
  }
  {
    float a = b2f(Kb[off]), b = b2f(Kb[off + 1]);
    Kb[off] = f2b(a * cs - b * sn);
    Kb[off + 1] = f2b(a * sn + b * cs);
  }
}

// ---------------- V transpose: V[B*S][H*64] -> Vt[bh][64][2048] ----------------
__global__ __launch_bounds__(256) void vtranspose(const short* __restrict__ V,
                                                  short* __restrict__ Vt) {
  __shared__ short T[64 * 72];
  int bh = blockIdx.y;
  int s0 = blockIdx.x * 64;
  int t = threadIdx.x;
  int r = t >> 2, cq = t & 3;
  const short* src = V + (size_t)((bh >> 4) * 2048 + s0 + r) * 1024 + (bh & 15) * 64 + cq * 16;
  *(int4*)(T + r * 72 + cq * 16) = *(const int4*)src;
  *(int4*)(T + r * 72 + cq * 16 + 8) = *(const int4*)(src + 8);
  __syncthreads();
  int d = t >> 2, sq = t & 3;
  short* dst = Vt + (size_t)bh * 131072 + (size_t)d * 2048 + s0 + sq * 16;
#pragma unroll
  for (int q = 0; q < 4; ++q) {
    short4v o;
#pragma unroll
    for (int j = 0; j < 4; ++j) o[j] = T[(sq * 16 + q * 4 + j) * 72 + d];
    *(short4v*)(dst + q * 4) = o;
  }
}

// ---------------- Flash attention v3: barrier-free, KVBLK=64, fixed-offset softmax
// grid 1024 x 256 thr; bh = bx&31; qt = 31-(bx>>5) (heavy blocks dispatch first).
// p = exp(s/8 - 24): ratio-exact vs true softmax (s/8 ~ N(0,1); overflow needs s/8>112).
// Denominator l via MFMA with B = ones (C-layout: each lane holds its own row's l).
__global__ __launch_bounds__(256) void attn3(const short* __restrict__ Q,
                                             const short* __restrict__ K,
                                             const short* __restrict__ Vt,
                                             short* __restrict__ O) {
  __shared__ __attribute__((aligned(16))) short Ptlds[4][64 * 20];
  int bx = blockIdx.x;
  int bh = bx & 31;
  int qt = 31 - (bx >> 5);
  int tid = threadIdx.x;
  int w = tid >> 6, lane = tid & 63;
  int l15 = lane & 15, lg = lane >> 4;
  int qbase = qt * 64 + w * 16;
  size_t rowbase = (size_t)(bh >> 4) * 2048 * 1024 + (size_t)(bh & 15) * 64;
  const short* vtb = Vt + (size_t)bh * 131072;
  bf16x8 qf[2];
  {
    const short* qp = Q + rowbase + (size_t)(qbase + l15) * 1024 + lg * 8;
    qf[0] = *(const bf16x8*)qp;
    qf[1] = *(const bf16x8*)(qp + 32);
  }
  bf16x8 ones;
#pragma unroll
  for (int j = 0; j < 8; ++j) ones[j] = (short)0x3F80;
  f32x4 oacc[4] = {};
  f32x4 lacc = {};
  int nchunk = qt + 1;  // 64-key chunks; uniform across waves
  short* pt = Ptlds[w];
  const short* Kb0 = K + rowbase;
  for (int kt = 0; kt < nchunk; ++kt) {
    int kstart = kt * 64;
    f32x4 s[4] = {};
#pragma unroll
    for (int g = 0; g < 4; ++g) {
      const short* kp = Kb0 + (size_t)(kstart + g * 16 + l15) * 1024 + lg * 8;
      bf16x8 k0 = *(const bf16x8*)kp;
      bf16x8 k1 = *(const bf16x8*)(kp + 32);
      s[g] = MFMA16(qf[0], k0, s[g]);
      s[g] = MFMA16(qf[1], k1, s[g]);
    }
    // p = exp(s/8 - 24), causal mask -> 0
#pragma unroll
    for (int g = 0; g < 4; ++g) {
      short4v pk;
#pragma unroll
      for (int r = 0; r < 4; ++r) {
        int qg = qbase + lg * 4 + r;
        int kg = kstart + g * 16 + l15;
        float v = __expf(s[g][r] * 0.125f - 24.f);
        pk[r] = f2b((kg > qg) ? 0.f : v);
      }
      *(short4v*)(pt + (g * 16 + l15) * 20 + lg * 4) = pk;
    }
    // P^T read as A-frags (within-wave LDS RAW: in-order DS, no barrier needed)
    bf16x8 pa0, pa1;
#pragma unroll
    for (int j = 0; j < 8; ++j) {
      pa0[j] = pt[(lg * 8 + j) * 20 + l15];
      pa1[j] = pt[(32 + lg * 8 + j) * 20 + l15];
    }
#pragma unroll
    for (int t = 0; t < 4; ++t) {
      const short* vp = vtb + (size_t)(t * 16 + l15) * 2048 + kstart + lg * 8;
      bf16x8 vf0 = *(const bf16x8*)vp;
      bf16x8 vf1 = *(const bf16x8*)(vp + 32);
      oacc[t] = MFMA16(pa0, vf0, oacc[t]);
      oacc[t] = MFMA16(pa1, vf1, oacc[t]);
    }
    lacc = MFMA16(pa0, ones, lacc);
    lacc = MFMA16(pa1, ones, lacc);
  }
#pragma unroll
  for (int t = 0; t < 4; ++t) {
#pragma unroll
    for (int r = 0; r < 4; ++r) {
      int row = qbase + lg * 4 + r;
      float denom = fmaxf(lacc[r], 1e-30f);
      O[rowbase + (size_t)row * 1024 + t * 16 + l15] = f2b(oacc[t][r] / denom);
    }
  }
}

extern "C" void kernel_launch(void* const* d_in, const int* in_sizes, int n_in,
                              void* d_out, int out_size, void* d_ws, size_t ws_size,
                              hipStream_t stream) {
  const float* xf = (const float*)d_in[0];
  const float* G1f = (const float*)d_in[8];
  const float* G2f = (const float*)d_in[9];
  char* ws = (char*)d_ws;
  const size_t MB = 1048576;
  short* Wslot = (short*)(ws);            // [0,8): WOb early, then W1/W3/W2
  short* WOb   = (short*)(ws);
  short* Wcat  = (short*)(ws + 8 * MB);   // [8,14): fused QKV weights
  short* Vt    = (short*)(ws + 8 * MB);   // [8,16): V^T (after Wcat dead)
  short* h     = (short*)(ws + 16 * MB);  // [16,24)
  short* Qb    = (short*)(ws + 24 * MB);  // [24,32)
  short* Kb    = (short*)(ws + 32 * MB);  // [32,40)
  short* Vb    = (short*)(ws + 40 * MB);  // [40,48)
  short* att   = (short*)(ws + 48 * MB);  // [48,56)
  short* w1x   = Qb;                      // [24,56): Q/K/V/att dead by FFN time
  float* x1f   = (float*)d_out;
  float* outf  = (float*)d_out;

  dim3 blk(256);
  convert_kernel<<<512, blk, 0, stream>>>((const float*)d_in[1], Wcat, 1048576);
  convert_kernel<<<512, blk, 0, stream>>>((const float*)d_in[2], Wcat + 1048576, 1048576);
  convert_kernel<<<512, blk, 0, stream>>>((const float*)d_in[3], Wcat + 2097152, 1048576);
  convert_kernel<<<512, blk, 0, stream>>>((const float*)d_in[4], WOb, 1048576);

  rmsnorm_f32<<<4096, blk, 0, stream>>>(xf, G1f, h);
  dim3 gqkv(24, 32);
  gemm_bt<3><<<gqkv, blk, 0, stream>>>(h, Wcat, nullptr, Qb, Kb, Vb, 4096, 1024, 1024);
  rope_kernel<<<8192, blk, 0, stream>>>(Qb, Kb);
  dim3 gvt(32, 32);
  vtranspose<<<gvt, blk, 0, stream>>>(Vb, Vt);
  attn3<<<1024, blk, 0, stream>>>(Qb, Kb, Vt, att);
  dim3 g1(8, 32);
  gemm_wide<<<g1, dim3(512), 0, stream>>>(att, WOb, xf, x1f, 4096, 1024, 1024);
  rmsnorm_f32<<<4096, blk, 0, stream>>>(x1f, G2f, h);
  dim3 g2(32, 32);
  convert_kernel<<<2048, blk, 0, stream>>>((const float*)d_in[5], Wslot, 4194304);
  gemm_bt<0><<<g2, blk, 0, stream>>>(h, Wslot, nullptr, w1x, nullptr, nullptr, 4096, 4096, 1024);
  convert_kernel<<<2048, blk, 0, stream>>>((const float*)d_in[7], Wslot, 4194304);
  gemm_bt<2><<<g2, blk, 0, stream>>>(h, Wslot, w1x, w1x, nullptr, nullptr, 4096, 4096, 1024);
  convert_kernel<<<2048, blk, 0, stream>>>((const float*)d_in[6], Wslot, 4194304);
  gemm_wide<<<g1, dim3(512), 0, stream>>>(w1x, Wslot, x1f, outf, 4096, 1024, 4096);
}